// Round 2
// baseline (603.106 us; speedup 1.0000x reference)
//
#include <hip/hip_runtime.h>
#include <hip/hip_bf16.h>

using bf16 = __hip_bfloat16;
typedef __bf16 bf16x8_t __attribute__((ext_vector_type(8)));
typedef __bf16 bf16x4_t __attribute__((ext_vector_type(4)));
typedef float f32x4  __attribute__((ext_vector_type(4)));
typedef float f32x16 __attribute__((ext_vector_type(16)));

#define AS1 __attribute__((address_space(1)))
#define AS3 __attribute__((address_space(3)))

// async 16B global->LDS. Dest is wave-uniform base + lane*16; callers pass
// per-lane dest = base + lane*16 so both semantics agree.
__device__ __forceinline__ void gll16(const void* g, void* l) {
  __builtin_amdgcn_global_load_lds((const AS1 void*)g, (AS3 void*)l, 16u, 0, 0u);
}

__device__ __forceinline__ __bf16 tobf(float f) {
  bf16 h = __float2bfloat16(f);
  return __builtin_bit_cast(__bf16, h);
}

// ---------------------------------------------------------------- cvt fp32->bf16
__global__ __launch_bounds__(256) void k_cvt(
    const float* __restrict__ x,  const float* __restrict__ wq,
    const float* __restrict__ wk, const float* __restrict__ wv,
    const float* __restrict__ wo,
    bf16* __restrict__ xb,  bf16* __restrict__ wqb, bf16* __restrict__ wkb,
    bf16* __restrict__ wvb, bf16* __restrict__ wob) {
  size_t id = (size_t)blockIdx.x * 256 + threadIdx.x;   // float4 units
  const float* s; bf16* d; size_t off;
  if (id < 2097152) { s = x; d = xb; off = id; }
  else {
    size_t r = id - 2097152;
    unsigned w = (unsigned)(r >> 20);
    off = r & 1048575u;
    s = (w == 0) ? wq : (w == 1) ? wk : (w == 2) ? wv : wo;
    d = (w == 0) ? wqb : (w == 1) ? wkb : (w == 2) ? wvb : wob;
  }
  const float4 v = ((const float4*)s)[off];
  bf16x4_t o = { tobf(v.x), tobf(v.y), tobf(v.z), tobf(v.w) };
  *(bf16x4_t*)(d + off * 4) = o;
}

// ---------------------------------------------------------------- lambda scalar
__global__ __launch_bounds__(256) void k_lam(
    const float* __restrict__ lq1, const float* __restrict__ lk1,
    const float* __restrict__ lq2, const float* __restrict__ lk2,
    float* __restrict__ lam) {
  __shared__ float r1[4], r2[4];
  int t = threadIdx.x;
  float a = lq1[t] * lk1[t];
  float b = lq2[t] * lk2[t];
#pragma unroll
  for (int s = 1; s < 64; s <<= 1) { a += __shfl_xor(a, s); b += __shfl_xor(b, s); }
  if ((t & 63) == 0) { r1[t >> 6] = a; r2[t >> 6] = b; }
  __syncthreads();
  if (t == 0) {
    float s1 = r1[0] + r1[1] + r1[2] + r1[3];
    float s2 = r2[0] + r2[1] + r2[2] + r2[3];
    *lam = expf(s1) - expf(s2) + 0.2f;
  }
}

// ---------------------------------------------------------------- GEMM core (NT)
// C[M,N] += A[M,K] * B[N,K]^T ; M-tile/N-tile = 128, BK = 64, K = 2048.
// 256 threads = 4 waves in 2x2; each wave 64x64 via 4x4 tiles of 16x16x32 MFMA.
// LDS XOR-swizzle: content at (row, c) = global chunk (c ^ (row&7)); reader
// fetches logical chunk cl at physical cl ^ (lane&7)  (row&7 == lane&7).
__device__ __forceinline__ void gemm_core(
    const bf16* __restrict__ A, const bf16* __restrict__ Bm,
    int m0, int n0, bf16* lA, bf16* lB, f32x4 (&acc)[4][4]) {
  const int tid  = threadIdx.x;
  const int lane = tid & 63;
  const int g    = lane >> 4;
  const int l15  = lane & 15;
  const int l7   = lane & 7;
  const int wave = tid >> 6;
  const int wm   = (wave >> 1) * 64;
  const int wn   = (wave & 1) * 64;

  int srow[4], ssc[4];
#pragma unroll
  for (int j = 0; j < 4; ++j) {
    int id = tid + j * 256;
    srow[j] = id >> 3;
    ssc[j]  = (id & 7) ^ (srow[j] & 7);
  }

  for (int k0 = 0; k0 < 2048; k0 += 64) {
    __syncthreads();
#pragma unroll
    for (int j = 0; j < 4; ++j) {
      int id = tid + j * 256;
      gll16(A  + (size_t)(m0 + srow[j]) * 2048 + k0 + ssc[j] * 8, lA + id * 8);
      gll16(Bm + (size_t)(n0 + srow[j]) * 2048 + k0 + ssc[j] * 8, lB + id * 8);
    }
    __syncthreads();
#pragma unroll
    for (int ks = 0; ks < 2; ++ks) {
      const int pc = (ks * 4 + g) ^ l7;
      bf16x8_t af[4], bfr[4];
#pragma unroll
      for (int mt = 0; mt < 4; ++mt)
        af[mt] = *(const bf16x8_t*)(lA + (wm + mt * 16 + l15) * 64 + pc * 8);
#pragma unroll
      for (int nt = 0; nt < 4; ++nt)
        bfr[nt] = *(const bf16x8_t*)(lB + (wn + nt * 16 + l15) * 64 + pc * 8);
#pragma unroll
      for (int mt = 0; mt < 4; ++mt)
#pragma unroll
        for (int nt = 0; nt < 4; ++nt)
          acc[mt][nt] = __builtin_amdgcn_mfma_f32_16x16x32_bf16(
              af[mt], bfr[nt], acc[mt][nt], 0, 0, 0);
    }
  }
}

// ---------------------------------------------------------------- QKV projection
// z=0: Q bf16 (4096,2048) ; z=1: K bf16 ; z=2: V transposed to (bh,hd,t)
__global__ __launch_bounds__(256) void k_gemm_qkv(
    const bf16* __restrict__ xb,
    const bf16* __restrict__ wqb, const bf16* __restrict__ wkb,
    const bf16* __restrict__ wvb,
    bf16* __restrict__ Qb, bf16* __restrict__ Kb, bf16* __restrict__ vt) {
  __shared__ __align__(16) bf16 lA[128 * 64];
  __shared__ __align__(16) bf16 lB[128 * 64];
  const int z  = blockIdx.z;
  const bf16* Bm = (z == 0) ? wqb : (z == 1) ? wkb : wvb;
  const int m0 = blockIdx.y * 128, n0 = blockIdx.x * 128;
  f32x4 acc[4][4] = {};
  gemm_core(xb, Bm, m0, n0, lA, lB, acc);

  const int lane = threadIdx.x & 63, wave = threadIdx.x >> 6;
  const int g = lane >> 4, l15 = lane & 15;
  const int wm = (wave >> 1) * 64, wn = (wave & 1) * 64;
  if (z < 2) {
    bf16* Out = z ? Kb : Qb;
#pragma unroll
    for (int mt = 0; mt < 4; ++mt)
#pragma unroll
      for (int nt = 0; nt < 4; ++nt) {
        int row = m0 + wm + mt * 16 + 4 * g;
        int col = n0 + wn + nt * 16 + l15;
#pragma unroll
        for (int r = 0; r < 4; ++r)
          Out[(size_t)(row + r) * 2048 + col] = __float2bfloat16(acc[mt][nt][r]);
      }
  } else {
#pragma unroll
    for (int mt = 0; mt < 4; ++mt)
#pragma unroll
      for (int nt = 0; nt < 4; ++nt) {
        int rb  = m0 + wm + mt * 16 + 4 * g;
        int col = n0 + wn + nt * 16 + l15;
        int nh = col >> 8, hd = col & 255;
        int b = rb >> 11, t = rb & 2047;
        bf16x4_t pv;
#pragma unroll
        for (int r = 0; r < 4; ++r) pv[r] = tobf(acc[mt][nt][r]);
        *(bf16x4_t*)(vt + ((size_t)((b * 8 + nh) * 256 + hd)) * 2048 + t) = pv;
      }
  }
}

// ---------------------------------------------------------------- output GEMM
__global__ __launch_bounds__(256) void k_gemm_out(
    const bf16* __restrict__ yb, const bf16* __restrict__ wob,
    float* __restrict__ outp) {
  __shared__ __align__(16) bf16 lA[128 * 64];
  __shared__ __align__(16) bf16 lB[128 * 64];
  const int m0 = blockIdx.y * 128, n0 = blockIdx.x * 128;
  f32x4 acc[4][4] = {};
  gemm_core(yb, wob, m0, n0, lA, lB, acc);
  const int lane = threadIdx.x & 63, wave = threadIdx.x >> 6;
  const int g = lane >> 4, l15 = lane & 15;
  const int wm = (wave >> 1) * 64, wn = (wave & 1) * 64;
#pragma unroll
  for (int mt = 0; mt < 4; ++mt)
#pragma unroll
    for (int nt = 0; nt < 4; ++nt) {
      int row = m0 + wm + mt * 16 + 4 * g;
      int col = n0 + wn + nt * 16 + l15;
#pragma unroll
      for (int r = 0; r < 4; ++r)
        outp[(size_t)(row + r) * 2048 + col] = acc[mt][nt][r] * 0.8f;
    }
}

// ---------------------------------------------------------------- rmsnorm+rotary
// Q/K (4096,2048) bf16 -> q1/q2/k1/k2 (4096, 8, 128) bf16.
// Rotary angle = nh * 10000^(-j/64)  (faithful to reference's head-axis bug).
__global__ __launch_bounds__(256) void k_rmsrot(
    const bf16* __restrict__ Qb, const bf16* __restrict__ Kb,
    bf16* __restrict__ q1, bf16* __restrict__ q2,
    bf16* __restrict__ k1, bf16* __restrict__ k2) {
  const int lane = threadIdx.x & 63, wave = threadIdx.x >> 6;
  const int task = blockIdx.x * 4 + wave;
  const int which = task & 1;
  const int p  = (task >> 1) & 1;
  const int nh = (task >> 2) & 7;
  const int tok = task >> 5;
  const bf16* src = (which ? Kb : Qb) + (size_t)tok * 2048 + nh * 256 + p * 128;
  float x1 = __bfloat162float(src[lane]);
  float x2 = __bfloat162float(src[lane + 64]);
  float ss = x1 * x1 + x2 * x2;
#pragma unroll
  for (int s = 1; s < 64; s <<= 1) ss += __shfl_xor(ss, s);
  float inv = rsqrtf(ss * (1.0f / 128.0f) + 1.1920929e-07f);
  float n1 = x1 * inv, n2 = x2 * inv;
  float fr = exp2f(-(float)lane * 0.20762050593045951f); // log2(10000)/64
  float ang = (float)nh * fr;
  float sn, cs;
  sincosf(ang, &sn, &cs);
  float o1 = n1 * cs + n2 * sn;
  float o2 = n2 * cs - n1 * sn;
  bf16* dst = (which ? (p ? k2 : k1) : (p ? q2 : q1)) + ((size_t)tok * 8 + nh) * 128;
  dst[lane]      = __float2bfloat16(o1);
  dst[lane + 64] = __float2bfloat16(o2);
}

// ---------------------------------------------------------------- flash attention
// grid (32, 16): x -> q-tile (descending for load balance), y -> (b, nh).
// 4 waves: wave = qg*2 + at ; each wave: 32 queries, one attention.
// S^T = K*Q^T and O^T = V^T*P via mfma_32x32x16_bf16; per-query softmax state
// lives at col = lane&31 (one shfl_xor(32) per reduction).
__global__ __launch_bounds__(256, 2) void k_flash(
    const bf16* __restrict__ q1b, const bf16* __restrict__ q2b,
    const bf16* __restrict__ k1b, const bf16* __restrict__ k2b,
    const bf16* __restrict__ vtb, const float* __restrict__ lamp,
    bf16* __restrict__ yb) {
  __shared__ __align__(16) bf16 smem[40960];  // 80 KB: k1|k2|v^T|P(4 waves)
  const int tid  = threadIdx.x;
  const int lane = tid & 63, wave = tid >> 6;
  const int qt = 31 - (int)blockIdx.x;
  const int bh = blockIdx.y;
  const int b = bh >> 3, nh = bh & 7;
  const int at = wave & 1, qg = wave >> 1;
  const int l31 = lane & 31, g5 = lane >> 5, l7 = lane & 7;
  const int q0 = qt * 64 + qg * 32;
  const int qglob = q0 + l31;

  bf16* lk = smem + (at ? 8192 : 0);
  bf16* lv = smem + 16384;
  bf16* lp = smem + 32768 + wave * 2048;

  // Q fragments (B-operand): lane holds q[query=l31][d = ks*16 + g5*8 .. +8]
  const bf16* qsrc = at ? q2b : q1b;
  bf16x8_t qf[8];
  {
    const bf16* qp = qsrc + ((size_t)(b * 2048 + qglob) * 8 + nh) * 128 + g5 * 8;
#pragma unroll
    for (int ks = 0; ks < 8; ++ks) qf[ks] = *(const bf16x8_t*)(qp + ks * 16);
  }

  f32x16 O[8] = {};
  float mrun = -1e30f, lrun = 0.f;
  const float scale = 0.08838834764831845f;  // 1/sqrt(128)

  for (int kt = 0; kt <= qt; ++kt) {
    const int k0 = kt * 64;
    __syncthreads();
    // stage k1, k2 (64 rows x 16 chunks each) and V^T (256 rows x 8 chunks)
#pragma unroll
    for (int it = 0; it < 4; ++it) {
      int id = tid + it * 256;
      int row = id >> 4, c = id & 15;
      int sc = (c & 8) | ((c & 7) ^ (row & 7));
      size_t goff = ((size_t)(b * 2048 + k0 + row) * 8 + nh) * 128 + sc * 8;
      gll16(k1b + goff, smem + id * 8);
      gll16(k2b + goff, smem + 8192 + id * 8);
    }
#pragma unroll
    for (int it = 0; it < 8; ++it) {
      int id = tid + it * 256;
      int row = id >> 3, c = id & 7;
      int sc = c ^ (row & 7);
      gll16(vtb + ((size_t)(bh * 256 + row)) * 2048 + k0 + sc * 8,
            smem + 16384 + id * 8);
    }
    __syncthreads();

    // S^T[key][query]
    f32x16 s0 = {}, s1 = {};
#pragma unroll
    for (int ks = 0; ks < 8; ++ks) {
      int cl = ks * 2 + g5;
      int pc = (cl & 8) | ((cl & 7) ^ l7);
      bf16x8_t a0 = *(const bf16x8_t*)(lk + (l31) * 128 + pc * 8);
      bf16x8_t a1 = *(const bf16x8_t*)(lk + (32 + l31) * 128 + pc * 8);
      s0 = __builtin_amdgcn_mfma_f32_32x32x16_bf16(a0, qf[ks], s0, 0, 0, 0);
      s1 = __builtin_amdgcn_mfma_f32_32x32x16_bf16(a1, qf[ks], s1, 0, 0, 0);
    }

    // scale + causal mask + online softmax (per-query = per lane col)
    const bool diag = (kt == qt);
    float rmax = -3.0e38f;
#pragma unroll
    for (int r = 0; r < 16; ++r) {
      int key0 = k0 + (r & 3) + 8 * (r >> 2) + 4 * g5;
      float v0 = s0[r] * scale;
      float v1 = s1[r] * scale;
      if (diag) {
        if (key0 > qglob)      v0 = -1e30f;
        if (key0 + 32 > qglob) v1 = -1e30f;
      }
      s0[r] = v0; s1[r] = v1;
      rmax = fmaxf(rmax, fmaxf(v0, v1));
    }
    rmax = fmaxf(rmax, __shfl_xor(rmax, 32));
    float mnew = fmaxf(mrun, rmax);
    float alpha = __expf(mrun - mnew);
    float psum = 0.f;
#pragma unroll
    for (int r = 0; r < 16; ++r) {
      float p0 = __expf(s0[r] - mnew);
      float p1 = __expf(s1[r] - mnew);
      s0[r] = p0; s1[r] = p1;
      psum += p0 + p1;
    }
    psum += __shfl_xor(psum, 32);
    lrun = lrun * alpha + psum;
    mrun = mnew;
#pragma unroll
    for (int i = 0; i < 8; ++i) O[i] *= alpha;

    // P -> LDS  (row = query, 64 keys, XOR-swizzled 16B chunks)
#pragma unroll
    for (int mt = 0; mt < 2; ++mt)
#pragma unroll
      for (int rq = 0; rq < 4; ++rq) {
        int ch = mt * 4 + rq;
        int pch = ch ^ (l31 & 7);
        bf16x4_t pv;
#pragma unroll
        for (int i = 0; i < 4; ++i)
          pv[i] = tobf(mt ? s1[rq * 4 + i] : s0[rq * 4 + i]);
        *(bf16x4_t*)(lp + l31 * 64 + pch * 8 + g5 * 4) = pv;
      }

    // O^T += V^T * P
#pragma unroll
    for (int ks2 = 0; ks2 < 4; ++ks2) {
      int cl = ks2 * 2 + g5;
      bf16x8_t pf = *(const bf16x8_t*)(lp + l31 * 64 + (cl ^ (l31 & 7)) * 8);
#pragma unroll
      for (int mt = 0; mt < 8; ++mt) {
        int vrow = mt * 32 + l31;
        bf16x8_t vf = *(const bf16x8_t*)(lv + vrow * 64 + (cl ^ l7) * 8);
        O[mt] = __builtin_amdgcn_mfma_f32_32x32x16_bf16(vf, pf, O[mt], 0, 0, 0);
      }
    }
  }

  // combine attn1 - lam*attn2 through LDS (reuse k/v region), write y bf16
  __syncthreads();
  const float lam = *lamp;
  const float invl = 1.f / lrun;
  bf16* cb = smem;  // [64 queries][stride 264]
  if (at) {
    const float f = lam * invl;
#pragma unroll
    for (int mt = 0; mt < 8; ++mt)
#pragma unroll
      for (int rq = 0; rq < 4; ++rq) {
        int hd = mt * 32 + 8 * rq + 4 * g5;
        bf16x4_t pv;
#pragma unroll
        for (int i = 0; i < 4; ++i) pv[i] = tobf(O[mt][rq * 4 + i] * f);
        *(bf16x4_t*)(cb + (size_t)(qg * 32 + l31) * 264 + hd) = pv;
      }
  }
  __syncthreads();
  if (!at) {
#pragma unroll
    for (int mt = 0; mt < 8; ++mt)
#pragma unroll
      for (int rq = 0; rq < 4; ++rq) {
        int hd = mt * 32 + 8 * rq + 4 * g5;
        bf16x4_t o2 = *(const bf16x4_t*)(cb + (size_t)(qg * 32 + l31) * 264 + hd);
        bf16x4_t pv;
#pragma unroll
        for (int i = 0; i < 4; ++i)
          pv[i] = tobf(O[mt][rq * 4 + i] * invl - (float)o2[i]);
        *(bf16x4_t*)(yb + (size_t)(b * 2048 + qglob) * 2048 + nh * 256 + hd) = pv;
      }
  }
}

// ---------------------------------------------------------------- launch
extern "C" void kernel_launch(void* const* d_in, const int* in_sizes, int n_in,
                              void* d_out, int out_size, void* d_ws, size_t ws_size,
                              hipStream_t stream) {
  (void)in_sizes; (void)n_in; (void)out_size; (void)ws_size;
  const float* x   = (const float*)d_in[0];
  const float* wq  = (const float*)d_in[1];
  const float* wk  = (const float*)d_in[2];
  const float* wv  = (const float*)d_in[3];
  const float* wo  = (const float*)d_in[4];
  const float* lq1 = (const float*)d_in[5];
  const float* lk1 = (const float*)d_in[6];
  const float* lq2 = (const float*)d_in[7];
  const float* lk2 = (const float*)d_in[8];
  float* out = (float*)d_out;

  char* p = (char*)d_ws;
  float* lam = (float*)p;            p += 256;
  bf16* xb  = (bf16*)p;              p += (size_t)4096 * 2048 * 2;
  bf16* wqb = (bf16*)p;              p += (size_t)2048 * 2048 * 2;
  bf16* wkb = (bf16*)p;              p += (size_t)2048 * 2048 * 2;
  bf16* wvb = (bf16*)p;              p += (size_t)2048 * 2048 * 2;
  bf16* wob = (bf16*)p;              p += (size_t)2048 * 2048 * 2;
  bf16* Qb  = (bf16*)p;              p += (size_t)4096 * 2048 * 2;
  bf16* Kb  = (bf16*)p;              p += (size_t)4096 * 2048 * 2;
  bf16* vt  = (bf16*)p;              p += (size_t)4096 * 2048 * 2;
  bf16* q1b = (bf16*)p;              p += (size_t)4096 * 1024 * 2;
  bf16* q2b = (bf16*)p;              p += (size_t)4096 * 1024 * 2;
  bf16* k1b = (bf16*)p;              p += (size_t)4096 * 1024 * 2;
  bf16* k2b = (bf16*)p;              p += (size_t)4096 * 1024 * 2;
  bf16* yb  = (bf16*)p;              p += (size_t)4096 * 2048 * 2;

  k_cvt<<<24576, 256, 0, stream>>>(x, wq, wk, wv, wo, xb, wqb, wkb, wvb, wob);
  k_lam<<<1, 256, 0, stream>>>(lq1, lk1, lq2, lk2, lam);
  k_gemm_qkv<<<dim3(16, 32, 3), 256, 0, stream>>>(xb, wqb, wkb, wvb, Qb, Kb, vt);
  k_rmsrot<<<32768, 256, 0, stream>>>(Qb, Kb, q1b, q2b, k1b, k2b);
  k_flash<<<dim3(32, 16), 256, 0, stream>>>(q1b, q2b, k1b, k2b, vt, lam, yb);
  k_gemm_out<<<dim3(16, 32), 256, 0, stream>>>(yb, wob, out);
}

// Round 3
// 461.157 us; speedup vs baseline: 1.3078x; 1.3078x over previous
//
#include <hip/hip_runtime.h>
#include <hip/hip_bf16.h>

using bf16 = __hip_bfloat16;
typedef __bf16 bf16x8_t __attribute__((ext_vector_type(8)));
typedef __bf16 bf16x4_t __attribute__((ext_vector_type(4)));
typedef float f32x4  __attribute__((ext_vector_type(4)));
typedef float f32x16 __attribute__((ext_vector_type(16)));

#define AS1 __attribute__((address_space(1)))
#define AS3 __attribute__((address_space(3)))

__device__ __forceinline__ void gll16(const void* g, void* l) {
  __builtin_amdgcn_global_load_lds((const AS1 void*)g, (AS3 void*)l, 16u, 0, 0u);
}

__device__ __forceinline__ __bf16 tobf(float f) {
  bf16 h = __float2bfloat16(f);
  return __builtin_bit_cast(__bf16, h);
}

// ---------------------------------------------------------------- cvt fp32->bf16
__global__ __launch_bounds__(256) void k_cvt(
    const float* __restrict__ x,  const float* __restrict__ wq,
    const float* __restrict__ wk, const float* __restrict__ wv,
    const float* __restrict__ wo,
    bf16* __restrict__ xb,  bf16* __restrict__ wqb, bf16* __restrict__ wkb,
    bf16* __restrict__ wvb, bf16* __restrict__ wob) {
  size_t id = (size_t)blockIdx.x * 256 + threadIdx.x;   // float4 units
  const float* s; bf16* d; size_t off;
  if (id < 2097152) { s = x; d = xb; off = id; }
  else {
    size_t r = id - 2097152;
    unsigned w = (unsigned)(r >> 20);
    off = r & 1048575u;
    s = (w == 0) ? wq : (w == 1) ? wk : (w == 2) ? wv : wo;
    d = (w == 0) ? wqb : (w == 1) ? wkb : (w == 2) ? wvb : wob;
  }
  const float4 v = ((const float4*)s)[off];
  bf16x4_t o = { tobf(v.x), tobf(v.y), tobf(v.z), tobf(v.w) };
  *(bf16x4_t*)(d + off * 4) = o;
}

// ---------------------------------------------------------------- lambda scalar
__global__ __launch_bounds__(256) void k_lam(
    const float* __restrict__ lq1, const float* __restrict__ lk1,
    const float* __restrict__ lq2, const float* __restrict__ lk2,
    float* __restrict__ lam) {
  __shared__ float r1[4], r2[4];
  int t = threadIdx.x;
  float a = lq1[t] * lk1[t];
  float b = lq2[t] * lk2[t];
#pragma unroll
  for (int s = 1; s < 64; s <<= 1) { a += __shfl_xor(a, s); b += __shfl_xor(b, s); }
  if ((t & 63) == 0) { r1[t >> 6] = a; r2[t >> 6] = b; }
  __syncthreads();
  if (t == 0) {
    float s1 = r1[0] + r1[1] + r1[2] + r1[3];
    float s2 = r2[0] + r2[1] + r2[2] + r2[3];
    *lam = expf(s1) - expf(s2) + 0.2f;
  }
}

// ---------------------------------------------------------------- GEMM core (NT)
__device__ __forceinline__ void gemm_core(
    const bf16* __restrict__ A, const bf16* __restrict__ Bm,
    int m0, int n0, bf16* lA, bf16* lB, f32x4 (&acc)[4][4]) {
  const int tid  = threadIdx.x;
  const int lane = tid & 63;
  const int g    = lane >> 4;
  const int l15  = lane & 15;
  const int l7   = lane & 7;
  const int wave = tid >> 6;
  const int wm   = (wave >> 1) * 64;
  const int wn   = (wave & 1) * 64;

  int srow[4], ssc[4];
#pragma unroll
  for (int j = 0; j < 4; ++j) {
    int id = tid + j * 256;
    srow[j] = id >> 3;
    ssc[j]  = (id & 7) ^ (srow[j] & 7);
  }

  for (int k0 = 0; k0 < 2048; k0 += 64) {
    __syncthreads();
#pragma unroll
    for (int j = 0; j < 4; ++j) {
      int id = tid + j * 256;
      gll16(A  + (size_t)(m0 + srow[j]) * 2048 + k0 + ssc[j] * 8, lA + id * 8);
      gll16(Bm + (size_t)(n0 + srow[j]) * 2048 + k0 + ssc[j] * 8, lB + id * 8);
    }
    __syncthreads();
#pragma unroll
    for (int ks = 0; ks < 2; ++ks) {
      const int pc = (ks * 4 + g) ^ l7;
      bf16x8_t af[4], bfr[4];
#pragma unroll
      for (int mt = 0; mt < 4; ++mt)
        af[mt] = *(const bf16x8_t*)(lA + (wm + mt * 16 + l15) * 64 + pc * 8);
#pragma unroll
      for (int nt = 0; nt < 4; ++nt)
        bfr[nt] = *(const bf16x8_t*)(lB + (wn + nt * 16 + l15) * 64 + pc * 8);
#pragma unroll
      for (int mt = 0; mt < 4; ++mt)
#pragma unroll
        for (int nt = 0; nt < 4; ++nt)
          acc[mt][nt] = __builtin_amdgcn_mfma_f32_16x16x32_bf16(
              af[mt], bfr[nt], acc[mt][nt], 0, 0, 0);
    }
  }
}

// ---------------------------------------------------------------- QKV projection
__global__ __launch_bounds__(256) void k_gemm_qkv(
    const bf16* __restrict__ xb,
    const bf16* __restrict__ wqb, const bf16* __restrict__ wkb,
    const bf16* __restrict__ wvb,
    bf16* __restrict__ Qb, bf16* __restrict__ Kb, bf16* __restrict__ vt) {
  __shared__ __align__(16) bf16 lA[128 * 64];
  __shared__ __align__(16) bf16 lB[128 * 64];
  const int z  = blockIdx.z;
  const bf16* Bm = (z == 0) ? wqb : (z == 1) ? wkb : wvb;
  const int m0 = blockIdx.y * 128, n0 = blockIdx.x * 128;
  f32x4 acc[4][4] = {};
  gemm_core(xb, Bm, m0, n0, lA, lB, acc);

  const int lane = threadIdx.x & 63, wave = threadIdx.x >> 6;
  const int g = lane >> 4, l15 = lane & 15;
  const int wm = (wave >> 1) * 64, wn = (wave & 1) * 64;
  if (z < 2) {
    bf16* Out = z ? Kb : Qb;
#pragma unroll
    for (int mt = 0; mt < 4; ++mt)
#pragma unroll
      for (int nt = 0; nt < 4; ++nt) {
        int row = m0 + wm + mt * 16 + 4 * g;
        int col = n0 + wn + nt * 16 + l15;
#pragma unroll
        for (int r = 0; r < 4; ++r)
          Out[(size_t)(row + r) * 2048 + col] = __float2bfloat16(acc[mt][nt][r]);
      }
  } else {
#pragma unroll
    for (int mt = 0; mt < 4; ++mt)
#pragma unroll
      for (int nt = 0; nt < 4; ++nt) {
        int rb  = m0 + wm + mt * 16 + 4 * g;
        int col = n0 + wn + nt * 16 + l15;
        int nh = col >> 8, hd = col & 255;
        int b = rb >> 11, t = rb & 2047;
        bf16x4_t pv;
#pragma unroll
        for (int r = 0; r < 4; ++r) pv[r] = tobf(acc[mt][nt][r]);
        *(bf16x4_t*)(vt + ((size_t)((b * 8 + nh) * 256 + hd)) * 2048 + t) = pv;
      }
  }
}

// ---------------------------------------------------------------- output GEMM
__global__ __launch_bounds__(256) void k_gemm_out(
    const bf16* __restrict__ yb, const bf16* __restrict__ wob,
    float* __restrict__ outp) {
  __shared__ __align__(16) bf16 lA[128 * 64];
  __shared__ __align__(16) bf16 lB[128 * 64];
  const int m0 = blockIdx.y * 128, n0 = blockIdx.x * 128;
  f32x4 acc[4][4] = {};
  gemm_core(yb, wob, m0, n0, lA, lB, acc);
  const int lane = threadIdx.x & 63, wave = threadIdx.x >> 6;
  const int g = lane >> 4, l15 = lane & 15;
  const int wm = (wave >> 1) * 64, wn = (wave & 1) * 64;
#pragma unroll
  for (int mt = 0; mt < 4; ++mt)
#pragma unroll
    for (int nt = 0; nt < 4; ++nt) {
      int row = m0 + wm + mt * 16 + 4 * g;
      int col = n0 + wn + nt * 16 + l15;
#pragma unroll
      for (int r = 0; r < 4; ++r)
        outp[(size_t)(row + r) * 2048 + col] = acc[mt][nt][r] * 0.8f;
    }
}

// ---------------------------------------------------------------- rmsnorm+rotary
__global__ __launch_bounds__(256) void k_rmsrot(
    const bf16* __restrict__ Qb, const bf16* __restrict__ Kb,
    bf16* __restrict__ q1, bf16* __restrict__ q2,
    bf16* __restrict__ k1, bf16* __restrict__ k2) {
  const int lane = threadIdx.x & 63, wave = threadIdx.x >> 6;
  const int task = blockIdx.x * 4 + wave;
  const int which = task & 1;
  const int p  = (task >> 1) & 1;
  const int nh = (task >> 2) & 7;
  const int tok = task >> 5;
  const bf16* src = (which ? Kb : Qb) + (size_t)tok * 2048 + nh * 256 + p * 128;
  float x1 = __bfloat162float(src[lane]);
  float x2 = __bfloat162float(src[lane + 64]);
  float ss = x1 * x1 + x2 * x2;
#pragma unroll
  for (int s = 1; s < 64; s <<= 1) ss += __shfl_xor(ss, s);
  float inv = rsqrtf(ss * (1.0f / 128.0f) + 1.1920929e-07f);
  float n1 = x1 * inv, n2 = x2 * inv;
  float fr = exp2f(-(float)lane * 0.20762050593045951f); // log2(10000)/64
  float ang = (float)nh * fr;
  float sn, cs;
  sincosf(ang, &sn, &cs);
  float o1 = n1 * cs + n2 * sn;
  float o2 = n2 * cs - n1 * sn;
  bf16* dst = (which ? (p ? k2 : k1) : (p ? q2 : q1)) + ((size_t)tok * 8 + nh) * 128;
  dst[lane]      = __float2bfloat16(o1);
  dst[lane + 64] = __float2bfloat16(o2);
}

// ---------------------------------------------------------------- flash attention
// 256 blocks (pair, bh): each block does q-tiles qtB=31-pair then qtA=pair
// -> exactly 33 k-iterations per block (perfect balance, 1 block/CU).
// Double-buffered K1/K2/V^T staging (2 x 64 KB LDS), ONE barrier per k-iter:
//   barrier -> issue async loads for next tile into buf^1 -> compute from buf.
// P (S-softmax) converted C-layout -> B-operand entirely in registers via
// __shfl_xor(32)  (no LDS round trip).
__global__ __launch_bounds__(256, 1) void k_flash(
    const bf16* __restrict__ q1b, const bf16* __restrict__ q2b,
    const bf16* __restrict__ k1b, const bf16* __restrict__ k2b,
    const bf16* __restrict__ vtb, const float* __restrict__ lamp,
    bf16* __restrict__ yb) {
  __shared__ __align__(16) bf16 smem[65536];  // 128 KB: 2 x (k1 8K|k2 8K|v 16K elems)
  const int tid  = threadIdx.x;
  const int lane = tid & 63, wave = tid >> 6;
  const int pair = blockIdx.x;           // 0..15
  const int bh = blockIdx.y;
  const int b = bh >> 3, nh = bh & 7;
  const int at = wave & 1, qg = wave >> 1;
  const int l31 = lane & 31, g5 = lane >> 5, l7 = lane & 7;
  const float scale = 0.08838834764831845f;  // 1/sqrt(128)
  const float lam = *lamp;

  auto stage = [&](int kt, int buf) {
    bf16* dst = smem + buf * 32768;
    const int k0 = kt * 64;
#pragma unroll
    for (int it = 0; it < 4; ++it) {
      int id = tid + it * 256;
      int row = id >> 4, c = id & 15;
      int sc = (c & 8) | ((c & 7) ^ (row & 7));
      size_t goff = ((size_t)(b * 2048 + k0 + row) * 8 + nh) * 128 + sc * 8;
      gll16(k1b + goff, dst + id * 8);
      gll16(k2b + goff, dst + 8192 + id * 8);
    }
#pragma unroll
    for (int it = 0; it < 8; ++it) {
      int id = tid + it * 256;
      int row = id >> 3, c = id & 7;
      int sc = c ^ (row & 7);
      gll16(vtb + ((size_t)(bh * 256 + row)) * 2048 + k0 + sc * 8,
            dst + 16384 + id * 8);
    }
  };

  bf16x8_t qf[8];
  auto loadQ = [&](int qt) {
    int qglob = qt * 64 + qg * 32 + l31;
    const bf16* qp = (at ? q2b : q1b) +
                     ((size_t)(b * 2048 + qglob) * 8 + nh) * 128 + g5 * 8;
#pragma unroll
    for (int ks = 0; ks < 8; ++ks) qf[ks] = *(const bf16x8_t*)(qp + ks * 16);
  };

  f32x16 O[8];
  float mrun, lrun;
  auto resetO = [&]() {
#pragma unroll
    for (int i = 0; i < 8; ++i)
#pragma unroll
      for (int j = 0; j < 16; ++j) O[i][j] = 0.f;
    mrun = -1e30f; lrun = 0.f;
  };

  auto step = [&](int kt, int buf, int qt) {
    const bf16* lk = smem + buf * 32768 + (at ? 8192 : 0);
    const bf16* lv = smem + buf * 32768 + 16384;
    const int k0 = kt * 64;
    const int qglob = qt * 64 + qg * 32 + l31;

    f32x16 s0, s1;
#pragma unroll
    for (int j = 0; j < 16; ++j) { s0[j] = 0.f; s1[j] = 0.f; }
#pragma unroll
    for (int ks = 0; ks < 8; ++ks) {
      int cl = ks * 2 + g5;
      int pc = (cl & 8) | ((cl & 7) ^ l7);
      bf16x8_t a0 = *(const bf16x8_t*)(lk + l31 * 128 + pc * 8);
      bf16x8_t a1 = *(const bf16x8_t*)(lk + (32 + l31) * 128 + pc * 8);
      s0 = __builtin_amdgcn_mfma_f32_32x32x16_bf16(a0, qf[ks], s0, 0, 0, 0);
      s1 = __builtin_amdgcn_mfma_f32_32x32x16_bf16(a1, qf[ks], s1, 0, 0, 0);
    }

    const bool diag = (kt == qt);
    float rmax = -3.0e38f;
#pragma unroll
    for (int r = 0; r < 16; ++r) {
      int key0 = k0 + (r & 3) + 8 * (r >> 2) + 4 * g5;
      float v0 = s0[r] * scale;
      float v1 = s1[r] * scale;
      if (diag) {
        if (key0 > qglob)      v0 = -1e30f;
        if (key0 + 32 > qglob) v1 = -1e30f;
      }
      s0[r] = v0; s1[r] = v1;
      rmax = fmaxf(rmax, fmaxf(v0, v1));
    }
    rmax = fmaxf(rmax, __shfl_xor(rmax, 32));
    float mnew = fmaxf(mrun, rmax);
    float alpha = __expf(mrun - mnew);
    float psum = 0.f;
#pragma unroll
    for (int r = 0; r < 16; ++r) {
      float p0 = __expf(s0[r] - mnew);
      float p1 = __expf(s1[r] - mnew);
      s0[r] = p0; s1[r] = p1;
      psum += p0 + p1;
    }
    psum += __shfl_xor(psum, 32);
    lrun = lrun * alpha + psum;
    mrun = mnew;
#pragma unroll
    for (int i = 0; i < 8; ++i) O[i] *= alpha;

    // PV: build P B-operand fragment in registers per 16-key slice
#pragma unroll
    for (int sl = 0; sl < 4; ++sl) {
      const int h = sl & 1;          // half within the 32-key S-tile
      bf16x4_t lo, hi;
#pragma unroll
      for (int j = 0; j < 4; ++j) {
        float vl = (sl < 2) ? s0[h * 8 + j]     : s1[h * 8 + j];
        float vh = (sl < 2) ? s0[h * 8 + 4 + j] : s1[h * 8 + 4 + j];
        lo[j] = tobf(vl); hi[j] = tobf(vh);
      }
      bf16x4_t send = g5 ? lo : hi;
      int2 si = __builtin_bit_cast(int2, send);
      int2 ri;
      ri.x = __shfl_xor(si.x, 32);
      ri.y = __shfl_xor(si.y, 32);
      bf16x4_t recv = __builtin_bit_cast(bf16x4_t, ri);
      bf16x4_t f0 = g5 ? recv : lo;
      bf16x4_t f1 = g5 ? hi : recv;
      bf16x8_t pf = { f0[0], f0[1], f0[2], f0[3], f1[0], f1[1], f1[2], f1[3] };

      const int cl = sl * 2 + g5;
#pragma unroll
      for (int mt = 0; mt < 8; ++mt) {
        bf16x8_t vf = *(const bf16x8_t*)(lv + (mt * 32 + l31) * 64 + (cl ^ l7) * 8);
        O[mt] = __builtin_amdgcn_mfma_f32_32x32x16_bf16(vf, pf, O[mt], 0, 0, 0);
      }
    }
  };

  auto finish = [&](int qt, bf16* cb) {
    const int qglob = qt * 64 + qg * 32 + l31;
    const float invl = 1.f / lrun;
    __syncthreads();
    if (at) {
      const float f = lam * invl;
#pragma unroll
      for (int mt = 0; mt < 8; ++mt)
#pragma unroll
        for (int rq = 0; rq < 4; ++rq) {
          int hd = mt * 32 + 8 * rq + 4 * g5;
          bf16x4_t pv;
#pragma unroll
          for (int i = 0; i < 4; ++i) pv[i] = tobf(O[mt][rq * 4 + i] * f);
          *(bf16x4_t*)(cb + (size_t)(qg * 32 + l31) * 264 + hd) = pv;
        }
    }
    __syncthreads();
    if (!at) {
#pragma unroll
      for (int mt = 0; mt < 8; ++mt)
#pragma unroll
        for (int rq = 0; rq < 4; ++rq) {
          int hd = mt * 32 + 8 * rq + 4 * g5;
          bf16x4_t o2 = *(const bf16x4_t*)(cb + (size_t)(qg * 32 + l31) * 264 + hd);
          bf16x4_t pv;
#pragma unroll
          for (int i = 0; i < 4; ++i)
            pv[i] = tobf(O[mt][rq * 4 + i] * invl - (float)o2[i]);
          *(bf16x4_t*)(yb + (size_t)(b * 2048 + qglob) * 2048 + nh * 256 + hd) = pv;
        }
    }
  };

  const int qtB = 31 - pair, qtA = pair;

  // ---- segment B (heavy tile)
  loadQ(qtB);
  resetO();
  stage(0, 0);
  for (int kt = 0; kt <= qtB; ++kt) {
    __syncthreads();
    if (kt < qtB) stage(kt + 1, (kt + 1) & 1);
    else          stage(0, (kt + 1) & 1);        // prefetch segment A kt=0
    step(kt, kt & 1, qtB);
  }
  finish(qtB, smem + (qtB & 1) * 32768);         // free buffer of segment B

  // ---- segment A (light tile)
  loadQ(qtA);
  resetO();
  for (int kt = 0; kt <= qtA; ++kt) {
    __syncthreads();
    if (kt < qtA) stage(kt + 1, (qtB + kt + 2) & 1);
    step(kt, (qtB + 1 + kt) & 1, qtA);
  }
  finish(qtA, smem + 32768);  // last-used buf is parity 0 (qtB+qtA+1 == 32)
}

// ---------------------------------------------------------------- launch
extern "C" void kernel_launch(void* const* d_in, const int* in_sizes, int n_in,
                              void* d_out, int out_size, void* d_ws, size_t ws_size,
                              hipStream_t stream) {
  (void)in_sizes; (void)n_in; (void)out_size; (void)ws_size;
  const float* x   = (const float*)d_in[0];
  const float* wq  = (const float*)d_in[1];
  const float* wk  = (const float*)d_in[2];
  const float* wv  = (const float*)d_in[3];
  const float* wo  = (const float*)d_in[4];
  const float* lq1 = (const float*)d_in[5];
  const float* lk1 = (const float*)d_in[6];
  const float* lq2 = (const float*)d_in[7];
  const float* lk2 = (const float*)d_in[8];
  float* out = (float*)d_out;

  char* p = (char*)d_ws;
  float* lam = (float*)p;            p += 256;
  bf16* xb  = (bf16*)p;              p += (size_t)4096 * 2048 * 2;
  bf16* wqb = (bf16*)p;              p += (size_t)2048 * 2048 * 2;
  bf16* wkb = (bf16*)p;              p += (size_t)2048 * 2048 * 2;
  bf16* wvb = (bf16*)p;              p += (size_t)2048 * 2048 * 2;
  bf16* wob = (bf16*)p;              p += (size_t)2048 * 2048 * 2;
  bf16* Qb  = (bf16*)p;              p += (size_t)4096 * 2048 * 2;
  bf16* Kb  = (bf16*)p;              p += (size_t)4096 * 2048 * 2;
  bf16* vt  = (bf16*)p;              p += (size_t)4096 * 2048 * 2;
  bf16* q1b = (bf16*)p;              p += (size_t)4096 * 1024 * 2;
  bf16* q2b = (bf16*)p;              p += (size_t)4096 * 1024 * 2;
  bf16* k1b = (bf16*)p;              p += (size_t)4096 * 1024 * 2;
  bf16* k2b = (bf16*)p;              p += (size_t)4096 * 1024 * 2;
  bf16* yb  = (bf16*)p;              p += (size_t)4096 * 2048 * 2;

  k_cvt<<<24576, 256, 0, stream>>>(x, wq, wk, wv, wo, xb, wqb, wkb, wvb, wob);
  k_lam<<<1, 256, 0, stream>>>(lq1, lk1, lq2, lk2, lam);
  k_gemm_qkv<<<dim3(16, 32, 3), 256, 0, stream>>>(xb, wqb, wkb, wvb, Qb, Kb, vt);
  k_rmsrot<<<32768, 256, 0, stream>>>(Qb, Kb, q1b, q2b, k1b, k2b);
  k_flash<<<dim3(16, 16), 256, 0, stream>>>(q1b, q2b, k1b, k2b, vt, lam, yb);
  k_gemm_out<<<dim3(16, 32), 256, 0, stream>>>(yb, wob, out);
}

// Round 4
// 431.189 us; speedup vs baseline: 1.3987x; 1.0695x over previous
//
#include <hip/hip_runtime.h>
#include <hip/hip_bf16.h>

using bf16 = __hip_bfloat16;
typedef __bf16 bf16x8_t __attribute__((ext_vector_type(8)));
typedef __bf16 bf16x4_t __attribute__((ext_vector_type(4)));
typedef float f32x4  __attribute__((ext_vector_type(4)));
typedef float f32x16 __attribute__((ext_vector_type(16)));

#define AS1 __attribute__((address_space(1)))
#define AS3 __attribute__((address_space(3)))

__device__ __forceinline__ void gll16(const void* g, void* l) {
  __builtin_amdgcn_global_load_lds((const AS1 void*)g, (AS3 void*)l, 16u, 0, 0u);
}

__device__ __forceinline__ __bf16 tobf(float f) {
  bf16 h = __float2bfloat16(f);
  return __builtin_bit_cast(__bf16, h);
}

// ---------------------------------------------------------------- cvt fp32->bf16
__global__ __launch_bounds__(256) void k_cvt(
    const float* __restrict__ x,  const float* __restrict__ wq,
    const float* __restrict__ wk, const float* __restrict__ wv,
    const float* __restrict__ wo,
    bf16* __restrict__ xb,  bf16* __restrict__ wqb, bf16* __restrict__ wkb,
    bf16* __restrict__ wvb, bf16* __restrict__ wob) {
  size_t id = (size_t)blockIdx.x * 256 + threadIdx.x;   // float4 units
  const float* s; bf16* d; size_t off;
  if (id < 2097152) { s = x; d = xb; off = id; }
  else {
    size_t r = id - 2097152;
    unsigned w = (unsigned)(r >> 20);
    off = r & 1048575u;
    s = (w == 0) ? wq : (w == 1) ? wk : (w == 2) ? wv : wo;
    d = (w == 0) ? wqb : (w == 1) ? wkb : (w == 2) ? wvb : wob;
  }
  const float4 v = ((const float4*)s)[off];
  bf16x4_t o = { tobf(v.x), tobf(v.y), tobf(v.z), tobf(v.w) };
  *(bf16x4_t*)(d + off * 4) = o;
}

// ---------------------------------------------------------------- lambda scalar
__global__ __launch_bounds__(256) void k_lam(
    const float* __restrict__ lq1, const float* __restrict__ lk1,
    const float* __restrict__ lq2, const float* __restrict__ lk2,
    float* __restrict__ lam) {
  __shared__ float r1[4], r2[4];
  int t = threadIdx.x;
  float a = lq1[t] * lk1[t];
  float b = lq2[t] * lk2[t];
#pragma unroll
  for (int s = 1; s < 64; s <<= 1) { a += __shfl_xor(a, s); b += __shfl_xor(b, s); }
  if ((t & 63) == 0) { r1[t >> 6] = a; r2[t >> 6] = b; }
  __syncthreads();
  if (t == 0) {
    float s1 = r1[0] + r1[1] + r1[2] + r1[3];
    float s2 = r2[0] + r2[1] + r2[2] + r2[3];
    *lam = expf(s1) - expf(s2) + 0.2f;
  }
}

// ---------------------------------------------------------------- GEMM core (NT)
// 2x2 wave tiling. SWAP=true accumulates with operands swapped so that the
// C/D reg-field indexes COLUMNS (4 consecutive per lane) -> vector stores.
template<bool SWAP>
__device__ __forceinline__ void gemm_core(
    const bf16* __restrict__ A, const bf16* __restrict__ Bm,
    int m0, int n0, bf16* lA, bf16* lB, f32x4 (&acc)[4][4]) {
  const int tid  = threadIdx.x;
  const int lane = tid & 63;
  const int g    = lane >> 4;
  const int l15  = lane & 15;
  const int l7   = lane & 7;
  const int wave = tid >> 6;
  const int wm   = (wave >> 1) * 64;
  const int wn   = (wave & 1) * 64;

  int srow[4], ssc[4];
#pragma unroll
  for (int j = 0; j < 4; ++j) {
    int id = tid + j * 256;
    srow[j] = id >> 3;
    ssc[j]  = (id & 7) ^ (srow[j] & 7);
  }

  for (int k0 = 0; k0 < 2048; k0 += 64) {
    __syncthreads();
#pragma unroll
    for (int j = 0; j < 4; ++j) {
      int id = tid + j * 256;
      gll16(A  + (size_t)(m0 + srow[j]) * 2048 + k0 + ssc[j] * 8, lA + id * 8);
      gll16(Bm + (size_t)(n0 + srow[j]) * 2048 + k0 + ssc[j] * 8, lB + id * 8);
    }
    __syncthreads();
#pragma unroll
    for (int ks = 0; ks < 2; ++ks) {
      const int pc = (ks * 4 + g) ^ l7;
      bf16x8_t af[4], bfr[4];
#pragma unroll
      for (int mt = 0; mt < 4; ++mt)
        af[mt] = *(const bf16x8_t*)(lA + (wm + mt * 16 + l15) * 64 + pc * 8);
#pragma unroll
      for (int nt = 0; nt < 4; ++nt)
        bfr[nt] = *(const bf16x8_t*)(lB + (wn + nt * 16 + l15) * 64 + pc * 8);
#pragma unroll
      for (int mt = 0; mt < 4; ++mt)
#pragma unroll
        for (int nt = 0; nt < 4; ++nt) {
          if (SWAP)
            acc[mt][nt] = __builtin_amdgcn_mfma_f32_16x16x32_bf16(
                bfr[nt], af[mt], acc[mt][nt], 0, 0, 0);
          else
            acc[mt][nt] = __builtin_amdgcn_mfma_f32_16x16x32_bf16(
                af[mt], bfr[nt], acc[mt][nt], 0, 0, 0);
        }
    }
  }
}

// ---------------------------------------------------------------- QKV projection
// z<2: 4x1 wave tiling (wave owns 32 rows x 128 cols = one full norm group per
// N-tile), swapped accumulation; fused rmsnorm + rotary epilogue writes
// q1/q2/k1/k2 directly. z=2: 2x2 unswapped; V transposed to (bh, hd, t).
__global__ __launch_bounds__(256) void k_gemm_qkv(
    const bf16* __restrict__ xb,
    const bf16* __restrict__ wqb, const bf16* __restrict__ wkb,
    const bf16* __restrict__ wvb,
    bf16* __restrict__ q1, bf16* __restrict__ q2,
    bf16* __restrict__ k1, bf16* __restrict__ k2,
    bf16* __restrict__ vt) {
  __shared__ __align__(16) bf16 lA[128 * 64];
  __shared__ __align__(16) bf16 lB[128 * 64];
  __shared__ float lCs[64], lSn[64];
  const int z  = blockIdx.z;
  const int m0 = blockIdx.y * 128, n0 = blockIdx.x * 128;
  const int tid = threadIdx.x;
  const int lane = tid & 63, wave = tid >> 6;
  const int g = lane >> 4, l15 = lane & 15, l7 = lane & 7;

  if (z < 2) {
    const bf16* Bm = z ? wkb : wqb;
    f32x4 acc[2][8] = {};

    int srow[4], ssc[4];
#pragma unroll
    for (int j = 0; j < 4; ++j) {
      int id = tid + j * 256;
      srow[j] = id >> 3;
      ssc[j]  = (id & 7) ^ (srow[j] & 7);
    }
    for (int k0 = 0; k0 < 2048; k0 += 64) {
      __syncthreads();
#pragma unroll
      for (int j = 0; j < 4; ++j) {
        int id = tid + j * 256;
        gll16(xb + (size_t)(m0 + srow[j]) * 2048 + k0 + ssc[j] * 8, lA + id * 8);
        gll16(Bm + (size_t)(n0 + srow[j]) * 2048 + k0 + ssc[j] * 8, lB + id * 8);
      }
      __syncthreads();
#pragma unroll
      for (int ks = 0; ks < 2; ++ks) {
        const int pc = (ks * 4 + g) ^ l7;
        bf16x8_t af[2], bfr[8];
#pragma unroll
        for (int mt = 0; mt < 2; ++mt)
          af[mt] = *(const bf16x8_t*)(lA + (wave * 32 + mt * 16 + l15) * 64 + pc * 8);
#pragma unroll
        for (int nt = 0; nt < 8; ++nt)
          bfr[nt] = *(const bf16x8_t*)(lB + (nt * 16 + l15) * 64 + pc * 8);
#pragma unroll
        for (int mt = 0; mt < 2; ++mt)
#pragma unroll
          for (int nt = 0; nt < 8; ++nt)
            acc[mt][nt] = __builtin_amdgcn_mfma_f32_16x16x32_bf16(
                bfr[nt], af[mt], acc[mt][nt], 0, 0, 0);
      }
    }

    // fused rmsnorm + rotary epilogue
    const int nh = n0 >> 8, p = (n0 >> 7) & 1;
    __syncthreads();
    if (tid < 64) {
      float fr = exp2f(-(float)tid * 0.20762050593045951f);  // log2(10000)/64
      float sn, cs;
      sincosf((float)nh * fr, &sn, &cs);
      lCs[tid] = cs; lSn[tid] = sn;
    }
    __syncthreads();
    bf16* dst = z ? (p ? k2 : k1) : (p ? q2 : q1);
#pragma unroll
    for (int mt = 0; mt < 2; ++mt) {
      float ss = 0.f;
#pragma unroll
      for (int nt = 0; nt < 8; ++nt)
#pragma unroll
        for (int r = 0; r < 4; ++r) ss += acc[mt][nt][r] * acc[mt][nt][r];
      ss += __shfl_xor(ss, 16);
      ss += __shfl_xor(ss, 32);
      const float inv = rsqrtf(ss * (1.0f / 128.0f) + 1.1920929e-07f);
      const int tok = m0 + wave * 32 + mt * 16 + l15;
      const size_t base = ((size_t)tok * 8 + nh) * 128;
#pragma unroll
      for (int nt4 = 0; nt4 < 4; ++nt4) {
        const int jb = nt4 * 16 + 4 * g;
        bf16x4_t o1v, o2v;
#pragma unroll
        for (int r = 0; r < 4; ++r) {
          float cs = lCs[jb + r], sn = lSn[jb + r];
          float x1 = acc[mt][nt4][r] * inv;
          float x2 = acc[mt][nt4 + 4][r] * inv;
          o1v[r] = tobf(x1 * cs + x2 * sn);
          o2v[r] = tobf(x2 * cs - x1 * sn);
        }
        *(bf16x4_t*)(dst + base + jb)      = o1v;
        *(bf16x4_t*)(dst + base + jb + 64) = o2v;
      }
    }
  } else {
    f32x4 acc[4][4] = {};
    gemm_core<false>(xb, wvb, m0, n0, lA, lB, acc);
    const int wm = (wave >> 1) * 64, wn = (wave & 1) * 64;
#pragma unroll
    for (int mt = 0; mt < 4; ++mt)
#pragma unroll
      for (int nt = 0; nt < 4; ++nt) {
        int rb  = m0 + wm + mt * 16 + 4 * g;
        int col = n0 + wn + nt * 16 + l15;
        int nh = col >> 8, hd = col & 255;
        int b = rb >> 11, t = rb & 2047;
        bf16x4_t pv;
#pragma unroll
        for (int r = 0; r < 4; ++r) pv[r] = tobf(acc[mt][nt][r]);
        *(bf16x4_t*)(vt + ((size_t)((b * 8 + nh) * 256 + hd)) * 2048 + t) = pv;
      }
  }
}

// ---------------------------------------------------------------- output GEMM
__global__ __launch_bounds__(256) void k_gemm_out(
    const bf16* __restrict__ yb, const bf16* __restrict__ wob,
    float* __restrict__ outp) {
  __shared__ __align__(16) bf16 lA[128 * 64];
  __shared__ __align__(16) bf16 lB[128 * 64];
  const int m0 = blockIdx.y * 128, n0 = blockIdx.x * 128;
  f32x4 acc[4][4] = {};
  gemm_core<true>(yb, wob, m0, n0, lA, lB, acc);
  const int lane = threadIdx.x & 63, wave = threadIdx.x >> 6;
  const int g = lane >> 4, l15 = lane & 15;
  const int wm = (wave >> 1) * 64, wn = (wave & 1) * 64;
#pragma unroll
  for (int mt = 0; mt < 4; ++mt)
#pragma unroll
    for (int nt = 0; nt < 4; ++nt) {
      int row = m0 + wm + mt * 16 + l15;        // col-field = row (swapped)
      int col = n0 + wn + nt * 16 + 4 * g;      // reg-field = 4 consecutive cols
      f32x4 v;
#pragma unroll
      for (int r = 0; r < 4; ++r) v[r] = acc[mt][nt][r] * 0.8f;
      *(f32x4*)(outp + (size_t)row * 2048 + col) = v;
    }
}

// ---------------------------------------------------------------- flash attention
// 256 blocks (pair, bh): q-tiles qtB=31-pair then qtA=pair -> 33 k-iters each.
// Double-buffered K1/K2/V^T staging, one barrier per k-iter; P stays in regs
// (shfl_xor(32) C->B layout conversion).
__global__ __launch_bounds__(256, 1) void k_flash(
    const bf16* __restrict__ q1b, const bf16* __restrict__ q2b,
    const bf16* __restrict__ k1b, const bf16* __restrict__ k2b,
    const bf16* __restrict__ vtb, const float* __restrict__ lamp,
    bf16* __restrict__ yb) {
  __shared__ __align__(16) bf16 smem[65536];  // 128 KB
  const int tid  = threadIdx.x;
  const int lane = tid & 63, wave = tid >> 6;
  const int pair = blockIdx.x;           // 0..15
  const int bh = blockIdx.y;
  const int b = bh >> 3, nh = bh & 7;
  const int at = wave & 1, qg = wave >> 1;
  const int l31 = lane & 31, g5 = lane >> 5, l7 = lane & 7;
  const float scale = 0.08838834764831845f;  // 1/sqrt(128)
  const float lam = *lamp;

  auto stage = [&](int kt, int buf) {
    bf16* dst = smem + buf * 32768;
    const int k0 = kt * 64;
#pragma unroll
    for (int it = 0; it < 4; ++it) {
      int id = tid + it * 256;
      int row = id >> 4, c = id & 15;
      int sc = (c & 8) | ((c & 7) ^ (row & 7));
      size_t goff = ((size_t)(b * 2048 + k0 + row) * 8 + nh) * 128 + sc * 8;
      gll16(k1b + goff, dst + id * 8);
      gll16(k2b + goff, dst + 8192 + id * 8);
    }
#pragma unroll
    for (int it = 0; it < 8; ++it) {
      int id = tid + it * 256;
      int row = id >> 3, c = id & 7;
      int sc = c ^ (row & 7);
      gll16(vtb + ((size_t)(bh * 256 + row)) * 2048 + k0 + sc * 8,
            dst + 16384 + id * 8);
    }
  };

  bf16x8_t qf[8];
  auto loadQ = [&](int qt) {
    int qglob = qt * 64 + qg * 32 + l31;
    const bf16* qp = (at ? q2b : q1b) +
                     ((size_t)(b * 2048 + qglob) * 8 + nh) * 128 + g5 * 8;
#pragma unroll
    for (int ks = 0; ks < 8; ++ks) qf[ks] = *(const bf16x8_t*)(qp + ks * 16);
  };

  f32x16 O[8];
  float mrun, lrun;
  auto resetO = [&]() {
#pragma unroll
    for (int i = 0; i < 8; ++i)
#pragma unroll
      for (int j = 0; j < 16; ++j) O[i][j] = 0.f;
    mrun = -1e30f; lrun = 0.f;
  };

  auto step = [&](int kt, int buf, int qt) {
    const bf16* lk = smem + buf * 32768 + (at ? 8192 : 0);
    const bf16* lv = smem + buf * 32768 + 16384;
    const int k0 = kt * 64;
    const int qglob = qt * 64 + qg * 32 + l31;

    f32x16 s0, s1;
#pragma unroll
    for (int j = 0; j < 16; ++j) { s0[j] = 0.f; s1[j] = 0.f; }
#pragma unroll
    for (int ks = 0; ks < 8; ++ks) {
      int cl = ks * 2 + g5;
      int pc = (cl & 8) | ((cl & 7) ^ l7);
      bf16x8_t a0 = *(const bf16x8_t*)(lk + l31 * 128 + pc * 8);
      bf16x8_t a1 = *(const bf16x8_t*)(lk + (32 + l31) * 128 + pc * 8);
      s0 = __builtin_amdgcn_mfma_f32_32x32x16_bf16(a0, qf[ks], s0, 0, 0, 0);
      s1 = __builtin_amdgcn_mfma_f32_32x32x16_bf16(a1, qf[ks], s1, 0, 0, 0);
    }

    const bool diag = (kt == qt);
    float rmax = -3.0e38f;
#pragma unroll
    for (int r = 0; r < 16; ++r) {
      int key0 = k0 + (r & 3) + 8 * (r >> 2) + 4 * g5;
      float v0 = s0[r] * scale;
      float v1 = s1[r] * scale;
      if (diag) {
        if (key0 > qglob)      v0 = -1e30f;
        if (key0 + 32 > qglob) v1 = -1e30f;
      }
      s0[r] = v0; s1[r] = v1;
      rmax = fmaxf(rmax, fmaxf(v0, v1));
    }
    rmax = fmaxf(rmax, __shfl_xor(rmax, 32));
    float mnew = fmaxf(mrun, rmax);
    float alpha = __expf(mrun - mnew);
    float psum = 0.f;
#pragma unroll
    for (int r = 0; r < 16; ++r) {
      float p0 = __expf(s0[r] - mnew);
      float p1 = __expf(s1[r] - mnew);
      s0[r] = p0; s1[r] = p1;
      psum += p0 + p1;
    }
    psum += __shfl_xor(psum, 32);
    lrun = lrun * alpha + psum;
    mrun = mnew;
#pragma unroll
    for (int i = 0; i < 8; ++i) O[i] *= alpha;

#pragma unroll
    for (int sl = 0; sl < 4; ++sl) {
      const int h = sl & 1;
      bf16x4_t lo, hi;
#pragma unroll
      for (int j = 0; j < 4; ++j) {
        float vl = (sl < 2) ? s0[h * 8 + j]     : s1[h * 8 + j];
        float vh = (sl < 2) ? s0[h * 8 + 4 + j] : s1[h * 8 + 4 + j];
        lo[j] = tobf(vl); hi[j] = tobf(vh);
      }
      bf16x4_t send = g5 ? lo : hi;
      int2 si = __builtin_bit_cast(int2, send);
      int2 ri;
      ri.x = __shfl_xor(si.x, 32);
      ri.y = __shfl_xor(si.y, 32);
      bf16x4_t recv = __builtin_bit_cast(bf16x4_t, ri);
      bf16x4_t f0 = g5 ? recv : lo;
      bf16x4_t f1 = g5 ? hi : recv;
      bf16x8_t pf = { f0[0], f0[1], f0[2], f0[3], f1[0], f1[1], f1[2], f1[3] };

      const int cl = sl * 2 + g5;
#pragma unroll
      for (int mt = 0; mt < 8; ++mt) {
        bf16x8_t vf = *(const bf16x8_t*)(lv + (mt * 32 + l31) * 64 + (cl ^ l7) * 8);
        O[mt] = __builtin_amdgcn_mfma_f32_32x32x16_bf16(vf, pf, O[mt], 0, 0, 0);
      }
    }
  };

  auto finish = [&](int qt, bf16* cb) {
    const int qglob = qt * 64 + qg * 32 + l31;
    const float invl = 1.f / lrun;
    __syncthreads();
    if (at) {
      const float f = lam * invl;
#pragma unroll
      for (int mt = 0; mt < 8; ++mt)
#pragma unroll
        for (int rq = 0; rq < 4; ++rq) {
          int hd = mt * 32 + 8 * rq + 4 * g5;
          bf16x4_t pv;
#pragma unroll
          for (int i = 0; i < 4; ++i) pv[i] = tobf(O[mt][rq * 4 + i] * f);
          *(bf16x4_t*)(cb + (size_t)(qg * 32 + l31) * 264 + hd) = pv;
        }
    }
    __syncthreads();
    if (!at) {
#pragma unroll
      for (int mt = 0; mt < 8; ++mt)
#pragma unroll
        for (int rq = 0; rq < 4; ++rq) {
          int hd = mt * 32 + 8 * rq + 4 * g5;
          bf16x4_t o2 = *(const bf16x4_t*)(cb + (size_t)(qg * 32 + l31) * 264 + hd);
          bf16x4_t pv;
#pragma unroll
          for (int i = 0; i < 4; ++i)
            pv[i] = tobf(O[mt][rq * 4 + i] * invl - (float)o2[i]);
          *(bf16x4_t*)(yb + (size_t)(b * 2048 + qglob) * 2048 + nh * 256 + hd) = pv;
        }
    }
  };

  const int qtB = 31 - pair, qtA = pair;

  loadQ(qtB);
  resetO();
  stage(0, 0);
  for (int kt = 0; kt <= qtB; ++kt) {
    __syncthreads();
    if (kt < qtB) stage(kt + 1, (kt + 1) & 1);
    else          stage(0, (kt + 1) & 1);        // prefetch segment A kt=0
    step(kt, kt & 1, qtB);
  }
  finish(qtB, smem + (qtB & 1) * 32768);

  loadQ(qtA);
  resetO();
  for (int kt = 0; kt <= qtA; ++kt) {
    __syncthreads();
    if (kt < qtA) stage(kt + 1, (qtB + kt + 2) & 1);
    step(kt, (qtB + 1 + kt) & 1, qtA);
  }
  finish(qtA, smem + 32768);
}

// ---------------------------------------------------------------- launch
extern "C" void kernel_launch(void* const* d_in, const int* in_sizes, int n_in,
                              void* d_out, int out_size, void* d_ws, size_t ws_size,
                              hipStream_t stream) {
  (void)in_sizes; (void)n_in; (void)out_size; (void)ws_size;
  const float* x   = (const float*)d_in[0];
  const float* wq  = (const float*)d_in[1];
  const float* wk  = (const float*)d_in[2];
  const float* wv  = (const float*)d_in[3];
  const float* wo  = (const float*)d_in[4];
  const float* lq1 = (const float*)d_in[5];
  const float* lk1 = (const float*)d_in[6];
  const float* lq2 = (const float*)d_in[7];
  const float* lk2 = (const float*)d_in[8];
  float* out = (float*)d_out;

  char* p = (char*)d_ws;
  float* lam = (float*)p;            p += 256;
  bf16* xb  = (bf16*)p;              p += (size_t)4096 * 2048 * 2;
  bf16* wqb = (bf16*)p;              p += (size_t)2048 * 2048 * 2;
  bf16* wkb = (bf16*)p;              p += (size_t)2048 * 2048 * 2;
  bf16* wvb = (bf16*)p;              p += (size_t)2048 * 2048 * 2;
  bf16* wob = (bf16*)p;              p += (size_t)2048 * 2048 * 2;
  bf16* vt  = (bf16*)p;              p += (size_t)4096 * 2048 * 2;
  bf16* q1b = (bf16*)p;              p += (size_t)4096 * 1024 * 2;
  bf16* q2b = (bf16*)p;              p += (size_t)4096 * 1024 * 2;
  bf16* k1b = (bf16*)p;              p += (size_t)4096 * 1024 * 2;
  bf16* k2b = (bf16*)p;              p += (size_t)4096 * 1024 * 2;
  bf16* yb  = (bf16*)p;              p += (size_t)4096 * 2048 * 2;

  k_cvt<<<24576, 256, 0, stream>>>(x, wq, wk, wv, wo, xb, wqb, wkb, wvb, wob);
  k_lam<<<1, 256, 0, stream>>>(lq1, lk1, lq2, lk2, lam);
  k_gemm_qkv<<<dim3(16, 32, 3), 256, 0, stream>>>(xb, wqb, wkb, wvb,
                                                  q1b, q2b, k1b, k2b, vt);
  k_flash<<<dim3(16, 16), 256, 0, stream>>>(q1b, q2b, k1b, k2b, vt, lam, yb);
  k_gemm_out<<<dim3(16, 32), 256, 0, stream>>>(yb, wob, out);
}